// Round 1
// baseline (215.416 us; speedup 1.0000x reference)
//
#include <hip/hip_runtime.h>

#define B_ 8
#define N_ 4096
#define F_ 512

// S (512 x 64) = [left | right | left_local | right_local], each [512][16] row-major.
__device__ __forceinline__ float Sval(const float* l, const float* r,
                                      const float* ll, const float* rl,
                                      int h, int e) {
    const int m = e >> 4, c = e & 15;
    const float* p = (m == 0) ? l : (m == 1) ? r : (m == 2) ? ll : rl;
    return p[h * 16 + c];
}

// GS = S^T S  (64x64). One block per row i.
__global__ __launch_bounds__(256) void k_gram(const float* l, const float* r,
                                              const float* ll, const float* rl,
                                              float* GS) {
    __shared__ float red[4][64];
    const int i = blockIdx.x;
    const int t = threadIdx.x;
    const int j = t & 63, seg = t >> 6;
    float acc = 0.f;
    const int h0 = seg * 128;
    for (int h = h0; h < h0 + 128; ++h)
        acc += Sval(l, r, ll, rl, h, i) * Sval(l, r, ll, rl, h, j);
    red[seg][j] = acc;
    __syncthreads();
    if (t < 64) GS[i * 64 + t] = red[0][t] + red[1][t] + red[2][t] + red[3][t];
}

// Per-batch: build CP (64x64), M = I - 0.5 CQ^T GS CP, invert (pivoted GJ),
// E = CP K CQ^T  ->  Eout[b] (64x64).
// smem layout (floats): CP [0,4096) | MI [4096,12416) stride 130 | AB [12416,14464)
// after GJ: Kc at [4096,8192), T1 at [8192,12288)  (MI dead by then)
__global__ __launch_bounds__(256) void k_build(const float* coeff, const float* gate,
                                               const float* coeff_l, const float* gate_l,
                                               const float* comm, const float* GS,
                                               float* Eout) {
    __shared__ float smem[14464];
    __shared__ float qs[64], u1s[32], u2s[32];
    __shared__ int piv_s;
#define MI(i, c) smem[4096 + (i) * 130 + (c)]
    float* CPs = smem;
    float* ABs = smem + 12416; // A [32][32] at 0, B at 1024

    const int b = blockIdx.x, t = threadIdx.x;
    const float g = gate[b], gl = gate_l[b];
    const float cs = comm[b] / 12.0f;

    if (t < 64) {
        float v;
        if (t < 16) v = 1.f;
        else if (t < 32) v = coeff[b * 16 + (t - 16)];
        else if (t < 48) v = 1.f;
        else v = coeff_l[b * 16 + (t - 48)];
        qs[t] = v;
    }
    if (t < 32) {
        u1s[t] = (t < 16) ? g * coeff[b * 16 + t] : -g;
        u2s[t] = (t < 16) ? gl * coeff_l[b * 16 + t] : -gl;
    }
    __syncthreads();

    // A[i][j] = v2s(i) u1s(j) GS[v2i(i)][j] ;  B[i][j] = v1s(i) u2s(j) GS[v1i(i)][32+j]
    for (int idx = t; idx < 2048; idx += 256) {
        const int which = idx >> 10;
        const int i = (idx >> 5) & 31, j = idx & 31;
        float val;
        if (which == 0) {
            const int v2i = (i < 16) ? 48 + i : 16 + i;
            const float v2sc = (i < 16) ? 1.f : coeff_l[b * 16 + (i - 16)];
            val = v2sc * u1s[j] * GS[v2i * 64 + j];
        } else {
            const int v1i = (i < 16) ? 16 + i : i - 16;
            const float v1sc = (i < 16) ? 1.f : coeff[b * 16 + (i - 16)];
            val = v1sc * u2s[j] * GS[v1i * 64 + 32 + j];
        }
        ABs[idx] = val;
    }
    __syncthreads();

    // CP
    for (int idx = t; idx < 4096; idx += 256) {
        const int e = idx >> 6, j = idx & 63;
        float val = 0.f;
        if (j < 32) {
            if (e == j) val += 0.5f * u1s[j];
            if (e >= 32) val += cs * u2s[e - 32] * ABs[(e - 32) * 32 + j];
        } else {
            const int jp = j - 32;
            if (e == 32 + jp) val += 0.5f * u2s[jp];
            if (e < 32) val -= cs * u1s[e] * ABs[1024 + e * 32 + jp];
        }
        CPs[idx] = val;
    }
    __syncthreads();

    // M (left half) + I (right half) into MI. M[i][m] = d(i,m) - 0.5 qs[i] * GS[i^16,:]·CP[:,m]
    {
        const int i = t & 63, grp = t >> 6;
        const float* gr = GS + (i ^ 16) * 64;
        for (int c = grp * 32; c < grp * 32 + 32; ++c) {
            float val;
            if (c < 64) {
                float d = 0.f;
                for (int e = 0; e < 64; ++e) d += gr[e] * CPs[e * 64 + c];
                val = ((i == c) ? 1.f : 0.f) - 0.5f * qs[i] * d;
            } else {
                val = ((c - 64) == i) ? 1.f : 0.f;
            }
            MI(i, c) = val;
        }
    }
    __syncthreads();

    // Gauss-Jordan with partial pivoting
    for (int k = 0; k < 64; ++k) {
        if (t < 64) {
            float val = (t >= k) ? fabsf(MI(t, k)) : -1.f;
            int idx = t;
            for (int off = 32; off > 0; off >>= 1) {
                const float ov = __shfl_xor(val, off);
                const int oi = __shfl_xor(idx, off);
                if (ov > val) { val = ov; idx = oi; }
            }
            if (t == 0) piv_s = idx;
        }
        __syncthreads();
        const int p = piv_s;
        if (p != k && t < 128) {
            const float tmp = MI(k, t);
            MI(k, t) = MI(p, t);
            MI(p, t) = tmp;
        }
        __syncthreads();
        const float d = MI(k, k);
        __syncthreads();
        if (t < 128) MI(k, t) = MI(k, t) * (1.0f / d);
        __syncthreads();
        const int r = t & 63, grp = t >> 6;
        const float f = MI(r, k);
        __syncthreads();
        if (r != k) {
            for (int c = grp * 32; c < grp * 32 + 32; ++c)
                MI(r, c) -= f * MI(k, c);
        }
        __syncthreads();
    }

    // compact K = MI[:,64:128) to smem[4096..8192) (register-staged: regions overlap)
    float kreg[16];
#pragma unroll
    for (int q = 0; q < 16; ++q) {
        const int idx = t * 16 + q;
        kreg[q] = MI(idx >> 6, 64 + (idx & 63));
    }
    __syncthreads();
#pragma unroll
    for (int q = 0; q < 16; ++q) smem[4096 + t * 16 + q] = kreg[q];
    __syncthreads();

    float* Kc = smem + 4096;
    float* T1 = smem + 8192;
    // T1 = CP * K
    for (int idx = t; idx < 4096; idx += 256) {
        const int e = idx >> 6, j = idx & 63;
        float d = 0.f;
        for (int q = 0; q < 64; ++q) d += CPs[e * 64 + q] * Kc[q * 64 + j];
        T1[idx] = d;
    }
    __syncthreads();
    // E[e][f] = qs[f^16] * T1[e][f^16]
    for (int idx = t; idx < 4096; idx += 256) {
        const int e = idx >> 6, f = idx & 63;
        Eout[b * 4096 + idx] = qs[f ^ 16] * T1[e * 64 + (f ^ 16)];
    }
#undef MI
}

// SE_b = S * E_b   (512 x 64). grid (hc=8, b=8)
__global__ __launch_bounds__(256) void k_se(const float* l, const float* r,
                                            const float* ll, const float* rl,
                                            const float* Ein, float* SEout) {
    __shared__ float Es[4096];
    const int b = blockIdx.y, hc = blockIdx.x, t = threadIdx.x;
    for (int idx = t; idx < 4096; idx += 256) Es[idx] = Ein[b * 4096 + idx];
    __syncthreads();
    const int h = hc * 64 + (t >> 2);
    const int mg = (t & 3) * 16;
    float acc[16];
#pragma unroll
    for (int q = 0; q < 16; ++q) acc[q] = 0.f;
#pragma unroll 4
    for (int e = 0; e < 64; ++e) {
        const float s = Sval(l, r, ll, rl, h, e);
        const float* Er = Es + e * 64 + mg;
#pragma unroll
        for (int q = 0; q < 16; ++q) acc[q] += s * Er[q];
    }
    float* o = SEout + (size_t)b * (512 * 64) + h * 64 + mg;
#pragma unroll
    for (int q = 0; q < 4; ++q) {
        float4 v;
        v.x = acc[q * 4 + 0]; v.y = acc[q * 4 + 1];
        v.z = acc[q * 4 + 2]; v.w = acc[q * 4 + 3];
        *reinterpret_cast<float4*>(o + q * 4) = v;
    }
}

// out = x + ((x * SE_b) * S^T).  grid (row-tile=64, b=8), 64 rows per block.
// smem: phase1 XsT[64][68] @0, SEs[64][68] @4352 ; phase2 ZsT[64][68] @0, SsT[64][132] @4352
__global__ __launch_bounds__(256) void k_mix(const float* x, const float* l, const float* r,
                                             const float* ll, const float* rl,
                                             const float* SE, float* out) {
    __shared__ float smem[12800];
    float* XsT = smem;
    float* SEs = smem + 4352;
    float* ZsT = smem;
    float* SsT = smem + 4352;

    const int b = blockIdx.y;
    const int r0 = blockIdx.x * 64;
    const int t = threadIdx.x;
    const int tx = t & 15, ty = t >> 4;
    const float* xb = x + (size_t)b * N_ * F_;
    float* outb = out + (size_t)b * N_ * F_;
    const float* SEb = SE + (size_t)b * (512 * 64);

    float acc[4][4];
#pragma unroll
    for (int i = 0; i < 4; ++i)
#pragma unroll
        for (int j = 0; j < 4; ++j) acc[i][j] = 0.f;

    const int lr = t >> 2;
    const int lc = (t & 3) * 16;

    // phase 1: Z[64][64] = X_tile[64][512] * SE[512][64]
    for (int kc = 0; kc < 8; ++kc) {
#pragma unroll
        for (int i = 0; i < 4; ++i) {
            const float4 v = *reinterpret_cast<const float4*>(
                xb + (size_t)(r0 + lr) * F_ + kc * 64 + lc + i * 4);
            XsT[(lc + i * 4 + 0) * 68 + lr] = v.x;
            XsT[(lc + i * 4 + 1) * 68 + lr] = v.y;
            XsT[(lc + i * 4 + 2) * 68 + lr] = v.z;
            XsT[(lc + i * 4 + 3) * 68 + lr] = v.w;
            const float4 w = *reinterpret_cast<const float4*>(
                SEb + (size_t)(kc * 64 + lr) * 64 + lc + i * 4);
            *reinterpret_cast<float4*>(&SEs[lr * 68 + lc + i * 4]) = w;
        }
        __syncthreads();
#pragma unroll 8
        for (int k = 0; k < 64; ++k) {
            const float4 a4 = *reinterpret_cast<const float4*>(&XsT[k * 68 + 4 * ty]);
            const float4 b4 = *reinterpret_cast<const float4*>(&SEs[k * 68 + 4 * tx]);
            const float av[4] = {a4.x, a4.y, a4.z, a4.w};
            const float bv[4] = {b4.x, b4.y, b4.z, b4.w};
#pragma unroll
            for (int i = 0; i < 4; ++i)
#pragma unroll
                for (int j = 0; j < 4; ++j) acc[i][j] += av[i] * bv[j];
        }
        __syncthreads();
    }

    // ZsT[m][r] = z[r][m]
#pragma unroll
    for (int j = 0; j < 4; ++j)
#pragma unroll
        for (int i = 0; i < 4; ++i)
            ZsT[(4 * tx + j) * 68 + 4 * ty + i] = acc[i][j];
    __syncthreads();

    // phase 2: out[64][512] = X + Z * S^T, h-chunks of 128
    for (int hc = 0; hc < 4; ++hc) {
        {
            const int gsel = t & 3;
            const int hl = t >> 2;
            const float* mat = (gsel == 0) ? l : (gsel == 1) ? r : (gsel == 2) ? ll : rl;
#pragma unroll
            for (int hh = 0; hh < 2; ++hh) {
                const int hloc = hl + hh * 64;
                const int h = hc * 128 + hloc;
#pragma unroll
                for (int q = 0; q < 4; ++q) {
                    const float4 v = *reinterpret_cast<const float4*>(mat + h * 16 + q * 4);
                    SsT[(gsel * 16 + q * 4 + 0) * 132 + hloc] = v.x;
                    SsT[(gsel * 16 + q * 4 + 1) * 132 + hloc] = v.y;
                    SsT[(gsel * 16 + q * 4 + 2) * 132 + hloc] = v.z;
                    SsT[(gsel * 16 + q * 4 + 3) * 132 + hloc] = v.w;
                }
            }
        }
        __syncthreads();

        float oacc[4][8];
#pragma unroll
        for (int i = 0; i < 4; ++i)
#pragma unroll
            for (int j = 0; j < 8; ++j) oacc[i][j] = 0.f;

#pragma unroll 8
        for (int e = 0; e < 64; ++e) {
            const float4 z4 = *reinterpret_cast<const float4*>(&ZsT[e * 68 + 4 * ty]);
            const float4 s0 = *reinterpret_cast<const float4*>(&SsT[e * 132 + 8 * tx]);
            const float4 s1 = *reinterpret_cast<const float4*>(&SsT[e * 132 + 8 * tx + 4]);
            const float zv[4] = {z4.x, z4.y, z4.z, z4.w};
            const float sv[8] = {s0.x, s0.y, s0.z, s0.w, s1.x, s1.y, s1.z, s1.w};
#pragma unroll
            for (int i = 0; i < 4; ++i)
#pragma unroll
                for (int j = 0; j < 8; ++j) oacc[i][j] += zv[i] * sv[j];
        }

#pragma unroll
        for (int i = 0; i < 4; ++i) {
            const size_t row = (size_t)(r0 + 4 * ty + i);
            const float* xr = xb + row * F_ + hc * 128 + 8 * tx;
            float* orow = outb + row * F_ + hc * 128 + 8 * tx;
            const float4 x0 = *reinterpret_cast<const float4*>(xr);
            const float4 x1 = *reinterpret_cast<const float4*>(xr + 4);
            float4 o0, o1;
            o0.x = x0.x + oacc[i][0]; o0.y = x0.y + oacc[i][1];
            o0.z = x0.z + oacc[i][2]; o0.w = x0.w + oacc[i][3];
            o1.x = x1.x + oacc[i][4]; o1.y = x1.y + oacc[i][5];
            o1.z = x1.z + oacc[i][6]; o1.w = x1.w + oacc[i][7];
            *reinterpret_cast<float4*>(orow) = o0;
            *reinterpret_cast<float4*>(orow + 4) = o1;
        }
        __syncthreads();
    }
}

extern "C" void kernel_launch(void* const* d_in, const int* in_sizes, int n_in,
                              void* d_out, int out_size, void* d_ws, size_t ws_size,
                              hipStream_t stream) {
    (void)in_sizes; (void)n_in; (void)out_size; (void)ws_size;
    const float* x       = (const float*)d_in[0];
    const float* coeff   = (const float*)d_in[1];
    const float* gate    = (const float*)d_in[2];
    const float* coeff_l = (const float*)d_in[3];
    const float* gate_l  = (const float*)d_in[4];
    const float* comm    = (const float*)d_in[5];
    const float* l       = (const float*)d_in[6];
    const float* r       = (const float*)d_in[7];
    const float* ll      = (const float*)d_in[8];
    const float* rl      = (const float*)d_in[9];

    float* wsf = (float*)d_ws;
    float* GS = wsf;                  // 4096 floats
    float* E  = wsf + 4096;           // 8 * 4096
    float* SE = wsf + 4096 + 8 * 4096;// 8 * 512 * 64
    float* out = (float*)d_out;

    k_gram<<<dim3(64), dim3(256), 0, stream>>>(l, r, ll, rl, GS);
    k_build<<<dim3(8), dim3(256), 0, stream>>>(coeff, gate, coeff_l, gate_l, comm, GS, E);
    k_se<<<dim3(8, 8), dim3(256), 0, stream>>>(l, r, ll, rl, E, SE);
    k_mix<<<dim3(64, 8), dim3(256), 0, stream>>>(x, l, r, ll, rl, SE, out);
}